// Round 2
// baseline (455.425 us; speedup 1.0000x reference)
//
#include <hip/hip_runtime.h>
#include <hip/hip_fp16.h>

// StaticGNN: 2-layer GCN. N=50000, E=800000, D=128, fp32 in/out.
// out = relu( D^{-1/2}(A+I)D^{-1/2} (X W_l) + b_l ), x2.
// H fp16; CSR recs int2{src,coef}.
// R16 = R15 with the workspace-layout bug fixed (R15 under-allocated h and wht:
// o_wht must be o_h + 3,200,000 words, o_y1h = o_wht + 16,384 words; R15's
// 1,600,000/8,192 made wht+y1h alias the upper half of h -> absmax 2.7).
// Mega-fusion unchanged: memset+count+scanA/B/C+gemm0+fill in ONE prep_kernel
// with fence-based grid syncs (768 blocks co-resident: LDS 37KB -> 4 blk/CU,
// launch_bounds(256,3) -> VGPR<=170 -> >=3 blk/CU; grid=3*256CU).
// 5 dispatches: memset(deg8+ctr), prep, agg1, gemm2, agg2.

#define D 128
#define WP 136   // LDS pitch (halves) for W^T tile
#define ABI 6    // vmem gathers per agg batch; 4 edges per inst
#define GRID_PREP 768   // 3 blocks/CU on 256 CUs -- co-resident guaranteed
#define GB_G 384        // phase-D blocks doing GEMM tiles; rest do CSR fill
#define NB_SCAN 196     // ceil(50000/256)

typedef _Float16 half8 __attribute__((ext_vector_type(8)));
typedef float floatx4 __attribute__((ext_vector_type(4)));

// ---------------- grid sync (CG-equivalent: release fence, device atomic,
// spin on agent-scope load, acquire fence) ----------------
__device__ inline void gsync(int* ctr, int target) {
    __syncthreads();
    if (threadIdx.x == 0) {
        __threadfence();              // release: drain + L2 writeback (agent scope)
        atomicAdd(ctr, 1);            // device-scope by default on CDNA
        while (__hip_atomic_load(ctr, __ATOMIC_RELAXED, __HIP_MEMORY_SCOPE_AGENT) < target)
            __builtin_amdgcn_s_sleep(2);
        __threadfence();              // acquire: invalidate L1 so plain loads see fresh data
    }
    __syncthreads();
}

// ---------------- shared device bodies ----------------

__device__ inline void stage_w(int tid, const __half* __restrict__ WhT, _Float16* wlds) {
#pragma unroll
    for (int q = 0; q < 8; ++q) {
        int idx = tid + q * 256;        // 0..2047, each = 8 halves
        int row = idx >> 4;
        int col8 = (idx & 15) * 8;
        const uint2* gsrc = (const uint2*)(WhT + row * 128 + col8);
        uint2 a = gsrc[0];
        uint2 b = gsrc[1];
        uint2* ldst = (uint2*)(wlds + row * WP + col8);
        ldst[0] = a;
        ldst[1] = b;
    }
}

__device__ inline void gemm_tile(int g, int tid,
                                 const float* __restrict__ Xf,
                                 const __half* __restrict__ Xh,
                                 __half* __restrict__ Hh, int n, int fromFloat,
                                 const _Float16* wlds) {
    const int wave = tid >> 6;
    const int lane = tid & 63;
    const int m = lane & 15;
    const int quad = lane >> 4;

    const int node = g * 64 + wave * 16 + m;
    const int node_ld = node < n ? node : (n - 1);

    half8 bfr[4];
    if (fromFloat) {
#pragma unroll
        for (int k = 0; k < 4; ++k) {
            const float4* p = (const float4*)(Xf + (size_t)node_ld * 128 + k * 32 + quad * 8);
            float4 lo = p[0];
            float4 hi = p[1];
            half8 h;
            h[0] = (_Float16)lo.x; h[1] = (_Float16)lo.y;
            h[2] = (_Float16)lo.z; h[3] = (_Float16)lo.w;
            h[4] = (_Float16)hi.x; h[5] = (_Float16)hi.y;
            h[6] = (_Float16)hi.z; h[7] = (_Float16)hi.w;
            bfr[k] = h;
        }
    } else {
#pragma unroll
        for (int k = 0; k < 4; ++k) {
            bfr[k] = *(const half8*)(Xh + (size_t)node_ld * 128 + k * 32 + quad * 8);
        }
    }

    floatx4 acc[8];
#pragma unroll
    for (int f = 0; f < 8; ++f) acc[f] = (floatx4){0.f, 0.f, 0.f, 0.f};

#pragma unroll
    for (int f = 0; f < 8; ++f) {
#pragma unroll
        for (int k = 0; k < 4; ++k) {
            half8 a = *(const half8*)(wlds + (f * 16 + m) * WP + k * 32 + quad * 8);
            acc[f] = __builtin_amdgcn_mfma_f32_16x16x32_f16(a, bfr[k], acc[f], 0, 0, 0);
        }
    }

    if (node < n) {
#pragma unroll
        for (int f = 0; f < 8; ++f) {
            __half2 p0 = __floats2half2_rn(acc[f][0], acc[f][1]);
            __half2 p1 = __floats2half2_rn(acc[f][2], acc[f][3]);
            uint2 pk;
            pk.x = *(unsigned int*)&p0;
            pk.y = *(unsigned int*)&p1;
            *(uint2*)(Hh + (size_t)node * 128 + f * 16 + quad * 4) = pk;
        }
    }
}

__device__ inline void gemm_body(int bid, int tid,
                                 const float* __restrict__ Xf,
                                 const __half* __restrict__ Xh,
                                 const __half* __restrict__ WhT,
                                 __half* __restrict__ Hh, int n, int fromFloat,
                                 _Float16* wlds) {
    stage_w(tid, WhT, wlds);
    __syncthreads();
    gemm_tile(bid, tid, Xf, Xh, Hh, n, fromFloat, wlds);
}

__device__ inline void fill_body(int i,
                                 const int* __restrict__ src,
                                 const int* __restrict__ dst,
                                 const int* __restrict__ rank,
                                 const int* __restrict__ row_ptr,
                                 const int* __restrict__ base8,
                                 const float* __restrict__ dinv,
                                 int2* __restrict__ recs, int e, int n) {
    if (i < e) {
        int d = dst[i];
        int s = src[i];
        int c = (i >> 8) & 7;   // copy keyed off edge index (matches count phase)
        int pos = row_ptr[d] + base8[c * n + d] + rank[i];
        int2 rec;
        rec.x = s;
        rec.y = __float_as_int(dinv[s] * dinv[d]);
        recs[pos] = rec;
    }
}

// ---------------- fused preprocessing + layer-0 GEMM + CSR fill ----------------
// Phase A: cvtw (W fp32 -> W^T fp16) + count (8-replica degree histogram + rank)
// Phase B: per-node degree + per-copy bases + in-block inclusive scan (regs persist)
// Phase C: every scan-block redoes the tiny 196-entry block-offset scan locally
//          (eliminates the scanB dispatch), writes row_ptr/dinv
// Phase D: role split: blocks [0,GB_G) GEMM tiles (grid-stride), rest CSR fill

__global__ __launch_bounds__(256, 3) void prep_kernel(
    const int* __restrict__ src, const int* __restrict__ dst,
    const float* __restrict__ x, const float* __restrict__ W,
    int* __restrict__ deg8, int* __restrict__ base8,
    int* __restrict__ partial,
    int* __restrict__ row_ptr, float* __restrict__ dinv,
    int* __restrict__ rank, int2* __restrict__ recs,
    __half* __restrict__ WhT, __half* __restrict__ Hh,
    int* ctr, int n, int e, int nbg) {
    __shared__ _Float16 wlds[128 * WP];
    __shared__ int sc[256];
    __shared__ int scb[256];
    const int tid = threadIdx.x;
    const int bid = blockIdx.x;
    const int gid = bid * 256 + tid;

    // ---- Phase A: cvtw + count ----
    if (gid < 2 * D * D) {
        int l = gid >> 14;
        int rem = gid & 16383;
        int f = rem >> 7;
        int k = rem & 127;
        WhT[gid] = __float2half(W[l * 16384 + k * 128 + f]);
    }
    for (int i = gid; i < e; i += GRID_PREP * 256) {
        int c = (i >> 8) & 7;
        rank[i] = atomicAdd(&deg8[c * n + dst[i]], 1);
    }
    gsync(ctr, GRID_PREP);

    // ---- Phase B: per-node degree + per-copy bases + in-block scan ----
    int mydeg = 0, myscan = 0;
    if (bid < NB_SCAN) {
        int i = gid;
        if (i < n) {
            int run = 0;
#pragma unroll
            for (int c = 0; c < 8; ++c) {
                base8[c * n + i] = run;
                run += deg8[c * n + i];
            }
            mydeg = run;
        }
        sc[tid] = mydeg;
        __syncthreads();
        for (int off = 1; off < 256; off <<= 1) {
            int v = (tid >= off) ? sc[tid - off] : 0;
            __syncthreads();
            sc[tid] += v;
            __syncthreads();
        }
        myscan = sc[tid];                   // inclusive within block
        if (tid == 255) partial[bid] = myscan;
    }
    gsync(ctr, 2 * GRID_PREP);

    // ---- Phase C: block-offset scan (per scan-block, replaces scanB dispatch) ----
    if (bid < NB_SCAN) {
        int p = (tid < NB_SCAN) ? partial[tid] : 0;
        scb[tid] = p;
        __syncthreads();
        for (int off = 1; off < 256; off <<= 1) {
            int v = (tid >= off) ? scb[tid - off] : 0;
            __syncthreads();
            scb[tid] += v;
            __syncthreads();
        }
        int boff = (bid == 0) ? 0 : scb[bid - 1];
        int i = gid;
        if (i < n) {
            row_ptr[i] = boff + myscan - mydeg;
            dinv[i] = rsqrtf((float)(mydeg + 1));
        }
        if (bid == 0 && tid == 0) row_ptr[n] = scb[NB_SCAN - 1];
    }
    gsync(ctr, 3 * GRID_PREP);

    // ---- Phase D: layer-0 GEMM (blocks [0,GB_G)) + CSR fill (rest) ----
    if (bid < GB_G) {
        stage_w(tid, WhT, wlds);
        __syncthreads();
        for (int g = bid; g < nbg; g += GB_G)
            gemm_tile(g, tid, x, nullptr, Hh, n, 1, wlds);
    } else {
        const int FB = GRID_PREP - GB_G;
        for (int i = (bid - GB_G) * 256 + tid; i < e; i += FB * 256)
            fill_body(i, src, dst, rank, row_ptr, base8, dinv, recs, e, n);
    }
}

// ---------------- layer-1 GEMM (fp16 input) ----------------

__global__ __launch_bounds__(256) void gemm_f16in_kernel(const __half* __restrict__ Xh,
                                                         const __half* __restrict__ WhT,
                                                         __half* __restrict__ Hh, int n) {
    __shared__ _Float16 wlds[128 * WP];
    gemm_body(blockIdx.x, threadIdx.x, nullptr, Xh, WhT, Hh, n, 0, wlds);
}

// ---------------- Aggregation (R10 quarter-wave structure, measured best) ----------------

__device__ inline void unpack8(uint4 u, float* f) {
    union { unsigned int x; __half2 h; } a, b, c, d;
    a.x = u.x; b.x = u.y; c.x = u.z; d.x = u.w;
    float2 f0 = __half22float2(a.h);
    float2 f1 = __half22float2(b.h);
    float2 f2 = __half22float2(c.h);
    float2 f3 = __half22float2(d.h);
    f[0] = f0.x; f[1] = f0.y; f[2] = f1.x; f[3] = f1.y;
    f[4] = f2.x; f[5] = f2.y; f[6] = f3.x; f[7] = f3.y;
}

__global__ __launch_bounds__(256) void agg_kernel(const __half* __restrict__ H,
                                                  const int2* __restrict__ recs,
                                                  const int* __restrict__ row_ptr,
                                                  const float* __restrict__ dinv,
                                                  const float* __restrict__ bias,
                                                  float* __restrict__ YF,
                                                  __half* __restrict__ YH,
                                                  int n, int writeHalf) {
    int wave = threadIdx.x >> 6;
    int lane = threadIdx.x & 63;
    int v = blockIdx.x * 4 + wave;
    if (v >= n) return;

    const int qw = lane >> 4;    // which edge of the quad
    const int fl = lane & 15;    // 8-feature (16B) slice
    const uint4* H16 = (const uint4*)H;  // row = 16 uint4

    float acc[8];
    {
        float di = dinv[v];
        float selfc = (qw == 0) ? di * di : 0.f;
        uint4 hv = H16[(size_t)v * 16 + fl];
        float f[8]; unpack8(hv, f);
#pragma unroll
        for (int t = 0; t < 8; ++t) acc[t] = f[t] * selfc;
    }

    int e0 = row_ptr[v];
    int e1 = row_ptr[v + 1];
    int e = e0;
    for (; e + 4 * ABI <= e1; e += 4 * ABI) {
        int2 r[ABI]; uint4 hu[ABI];
#pragma unroll
        for (int j = 0; j < ABI; ++j) r[j] = recs[e + 4 * j + qw];
#pragma unroll
        for (int j = 0; j < ABI; ++j) hu[j] = H16[(size_t)r[j].x * 16 + fl];
#pragma unroll
        for (int j = 0; j < ABI; ++j) {
            float c = __int_as_float(r[j].y);
            float f[8]; unpack8(hu[j], f);
#pragma unroll
            for (int t = 0; t < 8; ++t) acc[t] = fmaf(f[t], c, acc[t]);
        }
    }
    if (e < e1) {
        int2 r[ABI]; uint4 hu[ABI]; bool act[ABI];
#pragma unroll
        for (int j = 0; j < ABI; ++j) {
            int idx = e + 4 * j + qw;
            act[j] = idx < e1;
            if (act[j]) r[j] = recs[idx];
        }
#pragma unroll
        for (int j = 0; j < ABI; ++j) {
            if (act[j]) hu[j] = H16[(size_t)r[j].x * 16 + fl];
        }
#pragma unroll
        for (int j = 0; j < ABI; ++j) {
            if (act[j]) {
                float c = __int_as_float(r[j].y);
                float f[8]; unpack8(hu[j], f);
#pragma unroll
                for (int t = 0; t < 8; ++t) acc[t] = fmaf(f[t], c, acc[t]);
            }
        }
    }

#pragma unroll
    for (int t = 0; t < 8; ++t) {
        acc[t] += __shfl_xor(acc[t], 16);
        acc[t] += __shfl_xor(acc[t], 32);
    }

    if (qw == 0) {
        const float4* B4 = (const float4*)bias;
        float4 b0 = B4[fl * 2];
        float4 b1 = B4[fl * 2 + 1];
        float o[8];
        o[0] = fmaxf(acc[0] + b0.x, 0.f);
        o[1] = fmaxf(acc[1] + b0.y, 0.f);
        o[2] = fmaxf(acc[2] + b0.z, 0.f);
        o[3] = fmaxf(acc[3] + b0.w, 0.f);
        o[4] = fmaxf(acc[4] + b1.x, 0.f);
        o[5] = fmaxf(acc[5] + b1.y, 0.f);
        o[6] = fmaxf(acc[6] + b1.z, 0.f);
        o[7] = fmaxf(acc[7] + b1.w, 0.f);
        if (writeHalf) {
            __half2 p0 = __floats2half2_rn(o[0], o[1]);
            __half2 p1 = __floats2half2_rn(o[2], o[3]);
            __half2 p2 = __floats2half2_rn(o[4], o[5]);
            __half2 p3 = __floats2half2_rn(o[6], o[7]);
            uint4 pk;
            pk.x = *(unsigned int*)&p0;
            pk.y = *(unsigned int*)&p1;
            pk.z = *(unsigned int*)&p2;
            pk.w = *(unsigned int*)&p3;
            ((uint4*)YH)[(size_t)v * 16 + fl] = pk;
        } else {
            float4* Y4 = (float4*)YF;
            Y4[(size_t)v * 32 + fl * 2]     = make_float4(o[0], o[1], o[2], o[3]);
            Y4[(size_t)v * 32 + fl * 2 + 1] = make_float4(o[4], o[5], o[6], o[7]);
        }
    }
}

// ---------------- launch ----------------

extern "C" void kernel_launch(void* const* d_in, const int* in_sizes, int n_in,
                              void* d_out, int out_size, void* d_ws, size_t ws_size,
                              hipStream_t stream) {
    const float* x = (const float*)d_in[0];
    const int* ei = (const int*)d_in[1];
    const float* W = (const float*)d_in[2];
    const float* b = (const float*)d_in[3];
    float* out = (float*)d_out;

    const int N = in_sizes[0] / D;       // 50000
    const int E = in_sizes[1] / 2;       // 800000

    const int* src = ei;
    const int* dst = ei + E;

    int* wsi = (int*)d_ws;
    float* wsf = (float*)d_ws;
    const size_t o_deg8 = 0;                 // 8*N ints (memset 0, together with ctr)
    const size_t o_ctr  = o_deg8 + 400000;   // 16 ints (barrier counter)
    const size_t o_dinv = o_ctr + 16;        // N floats
    const size_t o_rp   = o_dinv + 50000;    // N+1 ints (pad 50016)
    const size_t o_part = o_rp + 50016;      // 256
    const size_t o_b8   = o_part + 256;      // 8*N ints
    const size_t o_rank = o_b8 + 400000;     // E ints
    const size_t o_rec  = o_rank + 800000;   // E int2 (region 16B-aligned)
    const size_t o_h    = o_rec + 1600000;   // N*128 halves = 3.2M 32-bit words
    const size_t o_wht  = o_h + 3200000;     // 2*128*128 halves = 16384 words
    const size_t o_y1h  = o_wht + 16384;     // N*128 halves = 3.2M words

    int* deg8    = wsi + o_deg8;
    int* ctr     = wsi + o_ctr;
    float* dinv  = wsf + o_dinv;
    int* row_ptr = wsi + o_rp;
    int* partial = wsi + o_part;
    int* base8   = wsi + o_b8;
    int* rank    = wsi + o_rank;
    int2* recs   = (int2*)(wsi + o_rec);
    __half* h    = (__half*)(wsi + o_h);
    __half* wht  = (__half*)(wsi + o_wht);
    __half* y1h  = (__half*)(wsi + o_y1h);

    const int nb_g = (N + 63) / 64;             // 782 GEMM tiles
    const int nb_a = (N + 3) / 4;               // 12500

    // zero deg8 + barrier counter in one memset
    hipMemsetAsync(deg8, 0, (size_t)(8 * 50000 + 16) * sizeof(int), stream);
    prep_kernel<<<GRID_PREP, 256, 0, stream>>>(src, dst, x, W,
                                               deg8, base8, partial, row_ptr, dinv,
                                               rank, recs, wht, h, ctr, N, E, nb_g);
    agg_kernel<<<nb_a, 256, 0, stream>>>(h, recs, row_ptr, dinv, b, nullptr, y1h, N, 1);
    gemm_f16in_kernel<<<nb_g, 256, 0, stream>>>(y1h, wht + 16384, h, N);
    agg_kernel<<<nb_a, 256, 0, stream>>>(h, recs, row_ptr, dinv, b + D, out, nullptr, N, 0);
}

// Round 3
// 244.472 us; speedup vs baseline: 1.8629x; 1.8629x over previous
//
#include <hip/hip_runtime.h>
#include <hip/hip_fp16.h>

// StaticGNN: 2-layer GCN. N=50000, E=800000, D=128, fp32 in/out.
// out = relu( D^{-1/2}(A+I)D^{-1/2} (X W_l) + b_l ), x2.
// H fp16; CSR recs int2{src,coef}.
// R17 = revert of R16's grid-sync mega-fusion (measured: each fence-based
// grid barrier costs ~70us on gfx950 -- wbl2/inv + hot-line spin; prep was
// 290us vs ~72us as separate dispatches). Back to R14 dispatch structure,
// plus two safe fusions on the measured-heavy side (agg path ~150us):
//  - scanB folded into scanC (each block locally rescans 196 partials)
//  - agg1+gemm2 fused into aggemm: block g aggregates its OWN 64 nodes into
//    an LDS y-tile, __syncthreads (block-local), then MFMA-GEMMs them.
//    No grid sync needed; GEMM writes to h2 (not h!) to avoid racing other
//    blocks' gathers from h.
// 7 dispatches: memset, count, scanA+cvtw, scanC2, gemmfill, aggemm, agg2.

#define D 128
#define WP 136   // LDS pitch (halves) for W^T tile
#define YP 136   // LDS pitch (halves) for y-tile in aggemm
#define ABI 6    // vmem gathers per agg batch; 4 edges per inst
#define NB_SCAN 196     // ceil(50000/256)

typedef _Float16 half8 __attribute__((ext_vector_type(8)));
typedef float floatx4 __attribute__((ext_vector_type(4)));

// ---------------- setup kernels ----------------

// deg8[8][n] zeroed by memset. Copy c = blockIdx&7. rank = within-copy rank.
__global__ void count_kernel(const int* __restrict__ dst, int* deg8,
                             int* __restrict__ rank, int e, int n) {
    int i = blockIdx.x * blockDim.x + threadIdx.x;
    int c = (blockIdx.x & 7) * n;
    if (i < e) rank[i] = atomicAdd(&deg8[c + dst[i]], 1);
}

// scanA: per-node total degree + per-copy exclusive bases; block sums -> partial.
// cvtw (W fp32 -> W^T fp16) fused as independent block-range tail.
__global__ __launch_bounds__(256) void scanA_cvtw_kernel(const int* __restrict__ deg8,
                                                         int* __restrict__ degT,
                                                         int* __restrict__ base8,
                                                         int* __restrict__ partial,
                                                         int n, int nbs,
                                                         const float* __restrict__ W,
                                                         __half* __restrict__ WhT) {
    __shared__ int red[4];
    int tid = threadIdx.x;
    int bid = blockIdx.x;
    if (bid < nbs) {
        int i = bid * 256 + tid;
        int tot = 0;
        if (i < n) {
            int run = 0;
#pragma unroll
            for (int c = 0; c < 8; ++c) {
                base8[c * n + i] = run;
                run += deg8[c * n + i];
            }
            degT[i] = run;
            tot = run;
        }
        for (int off = 32; off > 0; off >>= 1) tot += __shfl_down(tot, off, 64);
        if ((tid & 63) == 0) red[tid >> 6] = tot;
        __syncthreads();
        if (tid == 0) partial[bid] = red[0] + red[1] + red[2] + red[3];
    } else {
        // W[l][k][f] -> WhT[l][f][k]; 128 blocks x 256 threads = 32768 elems
        int id = (bid - nbs) * 256 + tid;
        int l = id >> 14;
        int rem = id & 16383;
        int f = rem >> 7;
        int k = rem & 127;
        WhT[id] = __float2half(W[l * 16384 + k * 128 + f]);
    }
}

// scanC2: scanB folded in -- every block locally scans the 196 partials,
// then does its in-block node scan. Writes row_ptr + dinv.
__global__ __launch_bounds__(256) void scanC2_kernel(const int* __restrict__ degT,
                                                     const int* __restrict__ partial,
                                                     int* __restrict__ row_ptr,
                                                     float* __restrict__ dinv, int n) {
    __shared__ int sc[256];
    __shared__ int scb[256];
    int tid = threadIdx.x;
    int bid = blockIdx.x;
    int p = (tid < NB_SCAN) ? partial[tid] : 0;
    scb[tid] = p;
    __syncthreads();
    for (int off = 1; off < 256; off <<= 1) {
        int v = (tid >= off) ? scb[tid - off] : 0;
        __syncthreads();
        scb[tid] += v;
        __syncthreads();
    }
    int i = bid * 256 + tid;
    int c = (i < n) ? degT[i] : 0;
    sc[tid] = c;
    __syncthreads();
    for (int off = 1; off < 256; off <<= 1) {
        int v = (tid >= off) ? sc[tid - off] : 0;
        __syncthreads();
        sc[tid] += v;
        __syncthreads();
    }
    if (i < n) {
        int base = ((bid == 0) ? 0 : scb[bid - 1]) + sc[tid] - c;
        row_ptr[i] = base;
        dinv[i] = rsqrtf((float)(c + 1));
    }
    if (bid == 0 && tid == 0) row_ptr[n] = scb[NB_SCAN - 1];
}

// ---------------- shared device bodies ----------------

__device__ inline void gemm_body(int bid, int tid,
                                 const float* __restrict__ Xf,
                                 const __half* __restrict__ WhT,
                                 __half* __restrict__ Hh, int n,
                                 _Float16* wlds) {
#pragma unroll
    for (int q = 0; q < 8; ++q) {
        int idx = tid + q * 256;        // 0..2047, each = 8 halves
        int row = idx >> 4;
        int col8 = (idx & 15) * 8;
        const uint2* gsrc = (const uint2*)(WhT + row * 128 + col8);
        uint2 a = gsrc[0];
        uint2 b = gsrc[1];
        uint2* ldst = (uint2*)(wlds + row * WP + col8);
        ldst[0] = a;
        ldst[1] = b;
    }
    __syncthreads();

    const int wave = tid >> 6;
    const int lane = tid & 63;
    const int m = lane & 15;
    const int quad = lane >> 4;

    const int node = bid * 64 + wave * 16 + m;
    const int node_ld = node < n ? node : (n - 1);

    half8 bfr[4];
#pragma unroll
    for (int k = 0; k < 4; ++k) {
        const float4* p = (const float4*)(Xf + (size_t)node_ld * 128 + k * 32 + quad * 8);
        float4 lo = p[0];
        float4 hi = p[1];
        half8 h;
        h[0] = (_Float16)lo.x; h[1] = (_Float16)lo.y;
        h[2] = (_Float16)lo.z; h[3] = (_Float16)lo.w;
        h[4] = (_Float16)hi.x; h[5] = (_Float16)hi.y;
        h[6] = (_Float16)hi.z; h[7] = (_Float16)hi.w;
        bfr[k] = h;
    }

    floatx4 acc[8];
#pragma unroll
    for (int f = 0; f < 8; ++f) acc[f] = (floatx4){0.f, 0.f, 0.f, 0.f};

#pragma unroll
    for (int f = 0; f < 8; ++f) {
#pragma unroll
        for (int k = 0; k < 4; ++k) {
            half8 a = *(const half8*)(wlds + (f * 16 + m) * WP + k * 32 + quad * 8);
            acc[f] = __builtin_amdgcn_mfma_f32_16x16x32_f16(a, bfr[k], acc[f], 0, 0, 0);
        }
    }

    if (node < n) {
#pragma unroll
        for (int f = 0; f < 8; ++f) {
            __half2 p0 = __floats2half2_rn(acc[f][0], acc[f][1]);
            __half2 p1 = __floats2half2_rn(acc[f][2], acc[f][3]);
            uint2 pk;
            pk.x = *(unsigned int*)&p0;
            pk.y = *(unsigned int*)&p1;
            *(uint2*)(Hh + (size_t)node * 128 + f * 16 + quad * 4) = pk;
        }
    }
}

__device__ inline void fill_body(int i,
                                 const int* __restrict__ src,
                                 const int* __restrict__ dst,
                                 const int* __restrict__ rank,
                                 const int* __restrict__ row_ptr,
                                 const int* __restrict__ base8,
                                 const float* __restrict__ dinv,
                                 int2* __restrict__ recs, int e, int n) {
    if (i < e) {
        int d = dst[i];
        int s = src[i];
        int c = (i >> 8) & 7;   // copy used by count (blockIdx&7, blockDim=256)
        int pos = row_ptr[d] + base8[c * n + d] + rank[i];
        int2 rec;
        rec.x = s;
        rec.y = __float_as_int(dinv[s] * dinv[d]);
        recs[pos] = rec;
    }
}

// ---------------- fused layer-0 GEMM + CSR fill (measured win: overlap) ----------------

__global__ __launch_bounds__(256) void gemmfill_kernel(const float* __restrict__ Xf,
                                                       const __half* __restrict__ WhT,
                                                       __half* __restrict__ Hh, int n, int nbg,
                                                       const int* __restrict__ src,
                                                       const int* __restrict__ dst,
                                                       const int* __restrict__ rank,
                                                       const int* __restrict__ row_ptr,
                                                       const int* __restrict__ base8,
                                                       const float* __restrict__ dinv,
                                                       int2* __restrict__ recs, int e) {
    __shared__ _Float16 wlds[128 * WP];
    int bid = blockIdx.x;
    int tid = threadIdx.x;
    if (bid < nbg) {
        gemm_body(bid, tid, Xf, WhT, Hh, n, wlds);
    } else {
        fill_body((bid - nbg) * 256 + tid, src, dst, rank, row_ptr, base8, dinv, recs, e, n);
    }
}

// ---------------- Aggregation core (R10 quarter-wave structure, measured best) ----------------

__device__ inline void unpack8(uint4 u, float* f) {
    union { unsigned int x; __half2 h; } a, b, c, d;
    a.x = u.x; b.x = u.y; c.x = u.z; d.x = u.w;
    float2 f0 = __half22float2(a.h);
    float2 f1 = __half22float2(b.h);
    float2 f2 = __half22float2(c.h);
    float2 f3 = __half22float2(d.h);
    f[0] = f0.x; f[1] = f0.y; f[2] = f1.x; f[3] = f1.y;
    f[4] = f2.x; f[5] = f2.y; f[6] = f3.x; f[7] = f3.y;
}

// Per-node edge walk: self-term + CSR edges. Partial sums per quarter-wave in acc[8].
__device__ inline void agg_row(int v, int qw, int fl,
                               const uint4* __restrict__ H16,
                               const int2* __restrict__ recs,
                               const int* __restrict__ row_ptr,
                               const float* __restrict__ dinv,
                               float* acc) {
    {
        float di = dinv[v];
        float selfc = (qw == 0) ? di * di : 0.f;
        uint4 hv = H16[(size_t)v * 16 + fl];
        float f[8]; unpack8(hv, f);
#pragma unroll
        for (int t = 0; t < 8; ++t) acc[t] = f[t] * selfc;
    }

    int e0 = row_ptr[v];
    int e1 = row_ptr[v + 1];
    int e = e0;
    for (; e + 4 * ABI <= e1; e += 4 * ABI) {
        int2 r[ABI]; uint4 hu[ABI];
#pragma unroll
        for (int j = 0; j < ABI; ++j) r[j] = recs[e + 4 * j + qw];
#pragma unroll
        for (int j = 0; j < ABI; ++j) hu[j] = H16[(size_t)r[j].x * 16 + fl];
#pragma unroll
        for (int j = 0; j < ABI; ++j) {
            float c = __int_as_float(r[j].y);
            float f[8]; unpack8(hu[j], f);
#pragma unroll
            for (int t = 0; t < 8; ++t) acc[t] = fmaf(f[t], c, acc[t]);
        }
    }
    if (e < e1) {
        int2 r[ABI]; uint4 hu[ABI]; bool act[ABI];
#pragma unroll
        for (int j = 0; j < ABI; ++j) {
            int idx = e + 4 * j + qw;
            act[j] = idx < e1;
            if (act[j]) r[j] = recs[idx];
        }
#pragma unroll
        for (int j = 0; j < ABI; ++j) {
            if (act[j]) hu[j] = H16[(size_t)r[j].x * 16 + fl];
        }
#pragma unroll
        for (int j = 0; j < ABI; ++j) {
            if (act[j]) {
                float c = __int_as_float(r[j].y);
                float f[8]; unpack8(hu[j], f);
#pragma unroll
                for (int t = 0; t < 8; ++t) acc[t] = fmaf(f[t], c, acc[t]);
            }
        }
    }
}

// Standalone agg (layer 1 -> fp32 out)
__global__ __launch_bounds__(256) void agg_kernel(const __half* __restrict__ H,
                                                  const int2* __restrict__ recs,
                                                  const int* __restrict__ row_ptr,
                                                  const float* __restrict__ dinv,
                                                  const float* __restrict__ bias,
                                                  float* __restrict__ YF, int n) {
    int wave = threadIdx.x >> 6;
    int lane = threadIdx.x & 63;
    int v = blockIdx.x * 4 + wave;
    if (v >= n) return;

    const int qw = lane >> 4;
    const int fl = lane & 15;
    const uint4* H16 = (const uint4*)H;

    float acc[8];
    agg_row(v, qw, fl, H16, recs, row_ptr, dinv, acc);

#pragma unroll
    for (int t = 0; t < 8; ++t) {
        acc[t] += __shfl_xor(acc[t], 16);
        acc[t] += __shfl_xor(acc[t], 32);
    }

    if (qw == 0) {
        const float4* B4 = (const float4*)bias;
        float4 b0 = B4[fl * 2];
        float4 b1 = B4[fl * 2 + 1];
        float4* Y4 = (float4*)YF;
        Y4[(size_t)v * 32 + fl * 2] = make_float4(
            fmaxf(acc[0] + b0.x, 0.f), fmaxf(acc[1] + b0.y, 0.f),
            fmaxf(acc[2] + b0.z, 0.f), fmaxf(acc[3] + b0.w, 0.f));
        Y4[(size_t)v * 32 + fl * 2 + 1] = make_float4(
            fmaxf(acc[4] + b1.x, 0.f), fmaxf(acc[5] + b1.y, 0.f),
            fmaxf(acc[6] + b1.z, 0.f), fmaxf(acc[7] + b1.w, 0.f));
    }
}

// ---------------- fused agg(layer0) + GEMM(layer1) ----------------
// Block g: 8 waves aggregate nodes [64g, 64g+64) (8 sequential nodes per wave)
// into LDS y-tile (fp16, pitch YP). Block-local barrier. Then the same 8 waves
// run the 64x128x128 MFMA tile (wave = (node-group, feature-half)), with W^T
// layer-1 fragments read directly from global (L2-hot, 32KB shared by all
// blocks). Output -> H2 (NOT H: other blocks still gather from H).
__global__ __launch_bounds__(512, 4) void aggemm_kernel(
    const __half* __restrict__ H,
    const int2* __restrict__ recs,
    const int* __restrict__ row_ptr,
    const float* __restrict__ dinv,
    const float* __restrict__ bias,       // layer-0 bias
    const __half* __restrict__ WhT2,      // layer-1 W^T
    __half* __restrict__ H2, int n) {
    __shared__ _Float16 yt[64 * YP];
    const int tid = threadIdx.x;
    const int wave = tid >> 6;
    const int lane = tid & 63;
    const int qw = lane >> 4;
    const int fl = lane & 15;
    const int g = blockIdx.x;
    const uint4* H16 = (const uint4*)H;

    // ---- phase 1: aggregate 8 nodes per wave into y-tile ----
    const float4* B4 = (const float4*)bias;
    float4 b0 = B4[fl * 2];
    float4 b1 = B4[fl * 2 + 1];
#pragma unroll 1
    for (int it = 0; it < 8; ++it) {
        int r = wave * 8 + it;           // local row 0..63
        int v = g * 64 + r;
        if (v < n) {
            float acc[8];
            agg_row(v, qw, fl, H16, recs, row_ptr, dinv, acc);
#pragma unroll
            for (int t = 0; t < 8; ++t) {
                acc[t] += __shfl_xor(acc[t], 16);
                acc[t] += __shfl_xor(acc[t], 32);
            }
            if (qw == 0) {
                __half2 p0 = __floats2half2_rn(fmaxf(acc[0] + b0.x, 0.f), fmaxf(acc[1] + b0.y, 0.f));
                __half2 p1 = __floats2half2_rn(fmaxf(acc[2] + b0.z, 0.f), fmaxf(acc[3] + b0.w, 0.f));
                __half2 p2 = __floats2half2_rn(fmaxf(acc[4] + b1.x, 0.f), fmaxf(acc[5] + b1.y, 0.f));
                __half2 p3 = __floats2half2_rn(fmaxf(acc[6] + b1.z, 0.f), fmaxf(acc[7] + b1.w, 0.f));
                uint4 pk;
                pk.x = *(unsigned int*)&p0;
                pk.y = *(unsigned int*)&p1;
                pk.z = *(unsigned int*)&p2;
                pk.w = *(unsigned int*)&p3;
                *(uint4*)&yt[r * YP + fl * 8] = pk;
            }
        } else if (qw == 0) {
            uint4 z = make_uint4(0, 0, 0, 0);
            *(uint4*)&yt[r * YP + fl * 8] = z;
        }
    }
    __syncthreads();

    // ---- phase 2: GEMM 64x128 @ W2 -> H2 ----
    const int mg = wave & 3;             // node-group (16 nodes)
    const int fh = wave >> 2;            // feature half (4 f-blocks)
    const int node = g * 64 + mg * 16 + fl;

    half8 bfr[4];
#pragma unroll
    for (int k = 0; k < 4; ++k)
        bfr[k] = *(const half8*)&yt[(mg * 16 + fl) * YP + k * 32 + qw * 8];

#pragma unroll
    for (int fb = 0; fb < 4; ++fb) {
        int f = fh * 4 + fb;
        floatx4 a4 = (floatx4){0.f, 0.f, 0.f, 0.f};
#pragma unroll
        for (int k = 0; k < 4; ++k) {
            half8 a = *(const half8*)(WhT2 + ((f * 16 + fl) * 128 + k * 32 + qw * 8));
            a4 = __builtin_amdgcn_mfma_f32_16x16x32_f16(a, bfr[k], a4, 0, 0, 0);
        }
        if (node < n) {
            __half2 p0 = __floats2half2_rn(a4[0], a4[1]);
            __half2 p1 = __floats2half2_rn(a4[2], a4[3]);
            uint2 pk;
            pk.x = *(unsigned int*)&p0;
            pk.y = *(unsigned int*)&p1;
            *(uint2*)(H2 + (size_t)node * 128 + f * 16 + qw * 4) = pk;
        }
    }
}

// ---------------- launch ----------------

extern "C" void kernel_launch(void* const* d_in, const int* in_sizes, int n_in,
                              void* d_out, int out_size, void* d_ws, size_t ws_size,
                              hipStream_t stream) {
    const float* x = (const float*)d_in[0];
    const int* ei = (const int*)d_in[1];
    const float* W = (const float*)d_in[2];
    const float* b = (const float*)d_in[3];
    float* out = (float*)d_out;

    const int N = in_sizes[0] / D;       // 50000
    const int E = in_sizes[1] / 2;       // 800000

    const int* src = ei;
    const int* dst = ei + E;

    int* wsi = (int*)d_ws;
    float* wsf = (float*)d_ws;
    const size_t o_deg8 = 0;                 // 8*N ints (memset 0)
    const size_t o_degT = o_deg8 + 400000;   // N ints
    const size_t o_dinv = o_degT + 50000;    // N floats
    const size_t o_rp   = o_dinv + 50000;    // N+1 ints (pad 50016)
    const size_t o_part = o_rp + 50016;      // 256
    const size_t o_boff = o_part + 256;      // 256 (unused, layout kept)
    const size_t o_b8   = o_boff + 256;      // 8*N ints
    const size_t o_rank = o_b8 + 400000;     // E ints
    const size_t o_rec  = o_rank + 800000;   // E int2 (region 16B-aligned)
    const size_t o_h    = o_rec + 1600000;   // N*128 halves = 3.2M words
    const size_t o_wht  = o_h + 3200000;     // 2*128*128 halves = 16384 words
    const size_t o_h2   = o_wht + 16384;     // N*128 halves (layer-1 GEMM out)

    int* deg8    = wsi + o_deg8;
    int* degT    = wsi + o_degT;
    float* dinv  = wsf + o_dinv;
    int* row_ptr = wsi + o_rp;
    int* partial = wsi + o_part;
    int* base8   = wsi + o_b8;
    int* rank    = wsi + o_rank;
    int2* recs   = (int2*)(wsi + o_rec);
    __half* h    = (__half*)(wsi + o_h);
    __half* wht  = (__half*)(wsi + o_wht);
    __half* h2   = (__half*)(wsi + o_h2);

    const int nb_e = (E + 255) / 256;           // 3125
    const int nb_s = (N + 255) / 256;           // 196
    const int nb_g = (N + 63) / 64;             // 782
    const int nb_a = (N + 3) / 4;               // 12500

    hipMemsetAsync(deg8, 0, (size_t)8 * 50000 * sizeof(int), stream);
    count_kernel<<<nb_e, 256, 0, stream>>>(dst, deg8, rank, E, N);
    scanA_cvtw_kernel<<<nb_s + 128, 256, 0, stream>>>(deg8, degT, base8, partial,
                                                      N, nb_s, W, wht);
    scanC2_kernel<<<nb_s, 256, 0, stream>>>(degT, partial, row_ptr, dinv, N);
    // fused: layer-0 GEMM (blocks [0,nb_g)) + CSR fill (blocks [nb_g,...))
    gemmfill_kernel<<<nb_g + nb_e, 256, 0, stream>>>(x, wht, h, N, nb_g,
                                                     src, dst, rank, row_ptr, base8,
                                                     dinv, recs, E);
    // fused: agg layer-0 + GEMM layer-1 (block-local, no grid sync needed)
    aggemm_kernel<<<nb_g, 512, 0, stream>>>(h, recs, row_ptr, dinv, b,
                                            wht + 16384, h2, N);
    agg_kernel<<<nb_a, 256, 0, stream>>>(h2, recs, row_ptr, dinv, b + D, out, N);
}

// Round 4
// 232.835 us; speedup vs baseline: 1.9560x; 1.0500x over previous
//
#include <hip/hip_runtime.h>
#include <hip/hip_fp16.h>

// StaticGNN: 2-layer GCN. N=50000, E=800000, D=128, fp32 in/out.
// out = relu( D^{-1/2}(A+I)D^{-1/2} (X W_l) + b_l ), x2.
// H fp16; CSR recs int2{src,coef}.
// R18 = R17 with aggemm re-tiled for occupancy: R17's aggemm measured
// 29.9% occupancy (782 blocks x 8 waves = 3 blk/CU; 8-row serial chain per
// wave + barrier) while no pipe was busy (hbm 17%, VALU 19%, MFMA 0.9%)
// -> latency-bound. New tile: 32 nodes / 512 threads / 4 rows per wave /
// grid 1563 -> 4 resident blocks/CU = 32 waves/CU, half the serial chain.
// 7 dispatches: memset, count, scanA+cvtw, scanC2, gemmfill, aggemm, agg2.

#define D 128
#define WP 136   // LDS pitch (halves) for W^T tile
#define YP 136   // LDS pitch (halves) for y-tile in aggemm
#define ABI 6    // vmem gathers per agg batch; 4 edges per inst
#define AGT 32   // aggemm node tile
#define NB_SCAN 196     // ceil(50000/256)

typedef _Float16 half8 __attribute__((ext_vector_type(8)));
typedef float floatx4 __attribute__((ext_vector_type(4)));

// ---------------- setup kernels ----------------

// deg8[8][n] zeroed by memset. Copy c = blockIdx&7. rank = within-copy rank.
__global__ void count_kernel(const int* __restrict__ dst, int* deg8,
                             int* __restrict__ rank, int e, int n) {
    int i = blockIdx.x * blockDim.x + threadIdx.x;
    int c = (blockIdx.x & 7) * n;
    if (i < e) rank[i] = atomicAdd(&deg8[c + dst[i]], 1);
}

// scanA: per-node total degree + per-copy exclusive bases; block sums -> partial.
// cvtw (W fp32 -> W^T fp16) fused as independent block-range tail.
__global__ __launch_bounds__(256) void scanA_cvtw_kernel(const int* __restrict__ deg8,
                                                         int* __restrict__ degT,
                                                         int* __restrict__ base8,
                                                         int* __restrict__ partial,
                                                         int n, int nbs,
                                                         const float* __restrict__ W,
                                                         __half* __restrict__ WhT) {
    __shared__ int red[4];
    int tid = threadIdx.x;
    int bid = blockIdx.x;
    if (bid < nbs) {
        int i = bid * 256 + tid;
        int tot = 0;
        if (i < n) {
            int run = 0;
#pragma unroll
            for (int c = 0; c < 8; ++c) {
                base8[c * n + i] = run;
                run += deg8[c * n + i];
            }
            degT[i] = run;
            tot = run;
        }
        for (int off = 32; off > 0; off >>= 1) tot += __shfl_down(tot, off, 64);
        if ((tid & 63) == 0) red[tid >> 6] = tot;
        __syncthreads();
        if (tid == 0) partial[bid] = red[0] + red[1] + red[2] + red[3];
    } else {
        // W[l][k][f] -> WhT[l][f][k]; 128 blocks x 256 threads = 32768 elems
        int id = (bid - nbs) * 256 + tid;
        int l = id >> 14;
        int rem = id & 16383;
        int f = rem >> 7;
        int k = rem & 127;
        WhT[id] = __float2half(W[l * 16384 + k * 128 + f]);
    }
}

// scanC2: scanB folded in -- every block locally scans the 196 partials,
// then does its in-block node scan. Writes row_ptr + dinv.
__global__ __launch_bounds__(256) void scanC2_kernel(const int* __restrict__ degT,
                                                     const int* __restrict__ partial,
                                                     int* __restrict__ row_ptr,
                                                     float* __restrict__ dinv, int n) {
    __shared__ int sc[256];
    __shared__ int scb[256];
    int tid = threadIdx.x;
    int bid = blockIdx.x;
    int p = (tid < NB_SCAN) ? partial[tid] : 0;
    scb[tid] = p;
    __syncthreads();
    for (int off = 1; off < 256; off <<= 1) {
        int v = (tid >= off) ? scb[tid - off] : 0;
        __syncthreads();
        scb[tid] += v;
        __syncthreads();
    }
    int i = bid * 256 + tid;
    int c = (i < n) ? degT[i] : 0;
    sc[tid] = c;
    __syncthreads();
    for (int off = 1; off < 256; off <<= 1) {
        int v = (tid >= off) ? sc[tid - off] : 0;
        __syncthreads();
        sc[tid] += v;
        __syncthreads();
    }
    if (i < n) {
        int base = ((bid == 0) ? 0 : scb[bid - 1]) + sc[tid] - c;
        row_ptr[i] = base;
        dinv[i] = rsqrtf((float)(c + 1));
    }
    if (bid == 0 && tid == 0) row_ptr[n] = scb[NB_SCAN - 1];
}

// ---------------- shared device bodies ----------------

__device__ inline void gemm_body(int bid, int tid,
                                 const float* __restrict__ Xf,
                                 const __half* __restrict__ WhT,
                                 __half* __restrict__ Hh, int n,
                                 _Float16* wlds) {
#pragma unroll
    for (int q = 0; q < 8; ++q) {
        int idx = tid + q * 256;        // 0..2047, each = 8 halves
        int row = idx >> 4;
        int col8 = (idx & 15) * 8;
        const uint2* gsrc = (const uint2*)(WhT + row * 128 + col8);
        uint2 a = gsrc[0];
        uint2 b = gsrc[1];
        uint2* ldst = (uint2*)(wlds + row * WP + col8);
        ldst[0] = a;
        ldst[1] = b;
    }
    __syncthreads();

    const int wave = tid >> 6;
    const int lane = tid & 63;
    const int m = lane & 15;
    const int quad = lane >> 4;

    const int node = bid * 64 + wave * 16 + m;
    const int node_ld = node < n ? node : (n - 1);

    half8 bfr[4];
#pragma unroll
    for (int k = 0; k < 4; ++k) {
        const float4* p = (const float4*)(Xf + (size_t)node_ld * 128 + k * 32 + quad * 8);
        float4 lo = p[0];
        float4 hi = p[1];
        half8 h;
        h[0] = (_Float16)lo.x; h[1] = (_Float16)lo.y;
        h[2] = (_Float16)lo.z; h[3] = (_Float16)lo.w;
        h[4] = (_Float16)hi.x; h[5] = (_Float16)hi.y;
        h[6] = (_Float16)hi.z; h[7] = (_Float16)hi.w;
        bfr[k] = h;
    }

    floatx4 acc[8];
#pragma unroll
    for (int f = 0; f < 8; ++f) acc[f] = (floatx4){0.f, 0.f, 0.f, 0.f};

#pragma unroll
    for (int f = 0; f < 8; ++f) {
#pragma unroll
        for (int k = 0; k < 4; ++k) {
            half8 a = *(const half8*)(wlds + (f * 16 + m) * WP + k * 32 + quad * 8);
            acc[f] = __builtin_amdgcn_mfma_f32_16x16x32_f16(a, bfr[k], acc[f], 0, 0, 0);
        }
    }

    if (node < n) {
#pragma unroll
        for (int f = 0; f < 8; ++f) {
            __half2 p0 = __floats2half2_rn(acc[f][0], acc[f][1]);
            __half2 p1 = __floats2half2_rn(acc[f][2], acc[f][3]);
            uint2 pk;
            pk.x = *(unsigned int*)&p0;
            pk.y = *(unsigned int*)&p1;
            *(uint2*)(Hh + (size_t)node * 128 + f * 16 + quad * 4) = pk;
        }
    }
}

__device__ inline void fill_body(int i,
                                 const int* __restrict__ src,
                                 const int* __restrict__ dst,
                                 const int* __restrict__ rank,
                                 const int* __restrict__ row_ptr,
                                 const int* __restrict__ base8,
                                 const float* __restrict__ dinv,
                                 int2* __restrict__ recs, int e, int n) {
    if (i < e) {
        int d = dst[i];
        int s = src[i];
        int c = (i >> 8) & 7;   // copy used by count (blockIdx&7, blockDim=256)
        int pos = row_ptr[d] + base8[c * n + d] + rank[i];
        int2 rec;
        rec.x = s;
        rec.y = __float_as_int(dinv[s] * dinv[d]);
        recs[pos] = rec;
    }
}

// ---------------- fused layer-0 GEMM + CSR fill (measured win: overlap) ----------------

__global__ __launch_bounds__(256) void gemmfill_kernel(const float* __restrict__ Xf,
                                                       const __half* __restrict__ WhT,
                                                       __half* __restrict__ Hh, int n, int nbg,
                                                       const int* __restrict__ src,
                                                       const int* __restrict__ dst,
                                                       const int* __restrict__ rank,
                                                       const int* __restrict__ row_ptr,
                                                       const int* __restrict__ base8,
                                                       const float* __restrict__ dinv,
                                                       int2* __restrict__ recs, int e) {
    __shared__ _Float16 wlds[128 * WP];
    int bid = blockIdx.x;
    int tid = threadIdx.x;
    if (bid < nbg) {
        gemm_body(bid, tid, Xf, WhT, Hh, n, wlds);
    } else {
        fill_body((bid - nbg) * 256 + tid, src, dst, rank, row_ptr, base8, dinv, recs, e, n);
    }
}

// ---------------- Aggregation core (R10 quarter-wave structure, measured best) ----------------

__device__ inline void unpack8(uint4 u, float* f) {
    union { unsigned int x; __half2 h; } a, b, c, d;
    a.x = u.x; b.x = u.y; c.x = u.z; d.x = u.w;
    float2 f0 = __half22float2(a.h);
    float2 f1 = __half22float2(b.h);
    float2 f2 = __half22float2(c.h);
    float2 f3 = __half22float2(d.h);
    f[0] = f0.x; f[1] = f0.y; f[2] = f1.x; f[3] = f1.y;
    f[4] = f2.x; f[5] = f2.y; f[6] = f3.x; f[7] = f3.y;
}

// Per-node edge walk: self-term + CSR edges. Partial sums per quarter-wave in acc[8].
__device__ inline void agg_row(int v, int qw, int fl,
                               const uint4* __restrict__ H16,
                               const int2* __restrict__ recs,
                               const int* __restrict__ row_ptr,
                               const float* __restrict__ dinv,
                               float* acc) {
    {
        float di = dinv[v];
        float selfc = (qw == 0) ? di * di : 0.f;
        uint4 hv = H16[(size_t)v * 16 + fl];
        float f[8]; unpack8(hv, f);
#pragma unroll
        for (int t = 0; t < 8; ++t) acc[t] = f[t] * selfc;
    }

    int e0 = row_ptr[v];
    int e1 = row_ptr[v + 1];
    int e = e0;
    for (; e + 4 * ABI <= e1; e += 4 * ABI) {
        int2 r[ABI]; uint4 hu[ABI];
#pragma unroll
        for (int j = 0; j < ABI; ++j) r[j] = recs[e + 4 * j + qw];
#pragma unroll
        for (int j = 0; j < ABI; ++j) hu[j] = H16[(size_t)r[j].x * 16 + fl];
#pragma unroll
        for (int j = 0; j < ABI; ++j) {
            float c = __int_as_float(r[j].y);
            float f[8]; unpack8(hu[j], f);
#pragma unroll
            for (int t = 0; t < 8; ++t) acc[t] = fmaf(f[t], c, acc[t]);
        }
    }
    if (e < e1) {
        int2 r[ABI]; uint4 hu[ABI]; bool act[ABI];
#pragma unroll
        for (int j = 0; j < ABI; ++j) {
            int idx = e + 4 * j + qw;
            act[j] = idx < e1;
            if (act[j]) r[j] = recs[idx];
        }
#pragma unroll
        for (int j = 0; j < ABI; ++j) {
            if (act[j]) hu[j] = H16[(size_t)r[j].x * 16 + fl];
        }
#pragma unroll
        for (int j = 0; j < ABI; ++j) {
            if (act[j]) {
                float c = __int_as_float(r[j].y);
                float f[8]; unpack8(hu[j], f);
#pragma unroll
                for (int t = 0; t < 8; ++t) acc[t] = fmaf(f[t], c, acc[t]);
            }
        }
    }
}

// Standalone agg (layer 1 -> fp32 out)
__global__ __launch_bounds__(256) void agg_kernel(const __half* __restrict__ H,
                                                  const int2* __restrict__ recs,
                                                  const int* __restrict__ row_ptr,
                                                  const float* __restrict__ dinv,
                                                  const float* __restrict__ bias,
                                                  float* __restrict__ YF, int n) {
    int wave = threadIdx.x >> 6;
    int lane = threadIdx.x & 63;
    int v = blockIdx.x * 4 + wave;
    if (v >= n) return;

    const int qw = lane >> 4;
    const int fl = lane & 15;
    const uint4* H16 = (const uint4*)H;

    float acc[8];
    agg_row(v, qw, fl, H16, recs, row_ptr, dinv, acc);

#pragma unroll
    for (int t = 0; t < 8; ++t) {
        acc[t] += __shfl_xor(acc[t], 16);
        acc[t] += __shfl_xor(acc[t], 32);
    }

    if (qw == 0) {
        const float4* B4 = (const float4*)bias;
        float4 b0 = B4[fl * 2];
        float4 b1 = B4[fl * 2 + 1];
        float4* Y4 = (float4*)YF;
        Y4[(size_t)v * 32 + fl * 2] = make_float4(
            fmaxf(acc[0] + b0.x, 0.f), fmaxf(acc[1] + b0.y, 0.f),
            fmaxf(acc[2] + b0.z, 0.f), fmaxf(acc[3] + b0.w, 0.f));
        Y4[(size_t)v * 32 + fl * 2 + 1] = make_float4(
            fmaxf(acc[4] + b1.x, 0.f), fmaxf(acc[5] + b1.y, 0.f),
            fmaxf(acc[6] + b1.z, 0.f), fmaxf(acc[7] + b1.w, 0.f));
    }
}

// ---------------- fused agg(layer0) + GEMM(layer1), 32-node tile ----------------
// Block g: 8 waves, wave aggregates 4 nodes of [32g, 32g+32) into LDS y-tile,
// block-local barrier, then 32x128 @ W2 MFMA tile (wave = (mg 0..1, fh 0..3),
// 2 f-blocks each). Output -> H2 (NOT H: other blocks still gather from H).
// Grid 1563 -> 6.1 blocks/CU offered vs 4 resident (wave-slot limit) -> full
// occupancy; 4-row serial chain halves barrier-wait variance vs R17.
__global__ __launch_bounds__(512, 8) void aggemm_kernel(
    const __half* __restrict__ H,
    const int2* __restrict__ recs,
    const int* __restrict__ row_ptr,
    const float* __restrict__ dinv,
    const float* __restrict__ bias,       // layer-0 bias
    const __half* __restrict__ WhT2,      // layer-1 W^T
    __half* __restrict__ H2, int n) {
    __shared__ _Float16 yt[AGT * YP];
    const int tid = threadIdx.x;
    const int wave = tid >> 6;
    const int lane = tid & 63;
    const int qw = lane >> 4;
    const int fl = lane & 15;
    const int g = blockIdx.x;
    const uint4* H16 = (const uint4*)H;

    // ---- phase 1: aggregate 4 nodes per wave into y-tile ----
    const float4* B4 = (const float4*)bias;
    float4 b0 = B4[fl * 2];
    float4 b1 = B4[fl * 2 + 1];
#pragma unroll 1
    for (int it = 0; it < 4; ++it) {
        int r = wave * 4 + it;           // local row 0..31
        int v = g * AGT + r;
        if (v < n) {
            float acc[8];
            agg_row(v, qw, fl, H16, recs, row_ptr, dinv, acc);
#pragma unroll
            for (int t = 0; t < 8; ++t) {
                acc[t] += __shfl_xor(acc[t], 16);
                acc[t] += __shfl_xor(acc[t], 32);
            }
            if (qw == 0) {
                __half2 p0 = __floats2half2_rn(fmaxf(acc[0] + b0.x, 0.f), fmaxf(acc[1] + b0.y, 0.f));
                __half2 p1 = __floats2half2_rn(fmaxf(acc[2] + b0.z, 0.f), fmaxf(acc[3] + b0.w, 0.f));
                __half2 p2 = __floats2half2_rn(fmaxf(acc[4] + b1.x, 0.f), fmaxf(acc[5] + b1.y, 0.f));
                __half2 p3 = __floats2half2_rn(fmaxf(acc[6] + b1.z, 0.f), fmaxf(acc[7] + b1.w, 0.f));
                uint4 pk;
                pk.x = *(unsigned int*)&p0;
                pk.y = *(unsigned int*)&p1;
                pk.z = *(unsigned int*)&p2;
                pk.w = *(unsigned int*)&p3;
                *(uint4*)&yt[r * YP + fl * 8] = pk;
            }
        } else if (qw == 0) {
            uint4 z = make_uint4(0, 0, 0, 0);
            *(uint4*)&yt[r * YP + fl * 8] = z;
        }
    }
    __syncthreads();

    // ---- phase 2: GEMM 32x128 @ W2 -> H2 ----
    const int mg = wave & 1;             // node-group (16 nodes)
    const int fh = wave >> 1;            // feature eighth-pair (2 f-blocks)
    const int node = g * AGT + mg * 16 + fl;

    half8 bfr[4];
#pragma unroll
    for (int k = 0; k < 4; ++k)
        bfr[k] = *(const half8*)&yt[(mg * 16 + fl) * YP + k * 32 + qw * 8];

#pragma unroll
    for (int fb = 0; fb < 2; ++fb) {
        int f = fh * 2 + fb;
        floatx4 a4 = (floatx4){0.f, 0.f, 0.f, 0.f};
#pragma unroll
        for (int k = 0; k < 4; ++k) {
            half8 a = *(const half8*)(WhT2 + ((f * 16 + fl) * 128 + k * 32 + qw * 8));
            a4 = __builtin_amdgcn_mfma_f32_16x16x32_f16(a, bfr[k], a4, 0, 0, 0);
        }
        if (node < n) {
            __half2 p0 = __floats2half2_rn(a4[0], a4[1]);
            __half2 p1 = __floats2half2_rn(a4[2], a4[3]);
            uint2 pk;
            pk.x = *(unsigned int*)&p0;
            pk.y = *(unsigned int*)&p1;
            *(uint2*)(H2 + (size_t)node * 128 + f * 16 + qw * 4) = pk;
        }
    }
}

// ---------------- launch ----------------

extern "C" void kernel_launch(void* const* d_in, const int* in_sizes, int n_in,
                              void* d_out, int out_size, void* d_ws, size_t ws_size,
                              hipStream_t stream) {
    const float* x = (const float*)d_in[0];
    const int* ei = (const int*)d_in[1];
    const float* W = (const float*)d_in[2];
    const float* b = (const float*)d_in[3];
    float* out = (float*)d_out;

    const int N = in_sizes[0] / D;       // 50000
    const int E = in_sizes[1] / 2;       // 800000

    const int* src = ei;
    const int* dst = ei + E;

    int* wsi = (int*)d_ws;
    float* wsf = (float*)d_ws;
    const size_t o_deg8 = 0;                 // 8*N ints (memset 0)
    const size_t o_degT = o_deg8 + 400000;   // N ints
    const size_t o_dinv = o_degT + 50000;    // N floats
    const size_t o_rp   = o_dinv + 50000;    // N+1 ints (pad 50016)
    const size_t o_part = o_rp + 50016;      // 256
    const size_t o_boff = o_part + 256;      // 256 (unused, layout kept)
    const size_t o_b8   = o_boff + 256;      // 8*N ints
    const size_t o_rank = o_b8 + 400000;     // E ints
    const size_t o_rec  = o_rank + 800000;   // E int2 (region 16B-aligned)
    const size_t o_h    = o_rec + 1600000;   // N*128 halves = 3.2M words
    const size_t o_wht  = o_h + 3200000;     // 2*128*128 halves = 16384 words
    const size_t o_h2   = o_wht + 16384;     // N*128 halves (layer-1 GEMM out)

    int* deg8    = wsi + o_deg8;
    int* degT    = wsi + o_degT;
    float* dinv  = wsf + o_dinv;
    int* row_ptr = wsi + o_rp;
    int* partial = wsi + o_part;
    int* base8   = wsi + o_b8;
    int* rank    = wsi + o_rank;
    int2* recs   = (int2*)(wsi + o_rec);
    __half* h    = (__half*)(wsi + o_h);
    __half* wht  = (__half*)(wsi + o_wht);
    __half* h2   = (__half*)(wsi + o_h2);

    const int nb_e = (E + 255) / 256;           // 3125
    const int nb_s = (N + 255) / 256;           // 196
    const int nb_g = (N + 63) / 64;             // 782
    const int nb_ag = (N + AGT - 1) / AGT;      // 1563
    const int nb_a = (N + 3) / 4;               // 12500

    hipMemsetAsync(deg8, 0, (size_t)8 * 50000 * sizeof(int), stream);
    count_kernel<<<nb_e, 256, 0, stream>>>(dst, deg8, rank, E, N);
    scanA_cvtw_kernel<<<nb_s + 128, 256, 0, stream>>>(deg8, degT, base8, partial,
                                                      N, nb_s, W, wht);
    scanC2_kernel<<<nb_s, 256, 0, stream>>>(degT, partial, row_ptr, dinv, N);
    // fused: layer-0 GEMM (blocks [0,nb_g)) + CSR fill (blocks [nb_g,...))
    gemmfill_kernel<<<nb_g + nb_e, 256, 0, stream>>>(x, wht, h, N, nb_g,
                                                     src, dst, rank, row_ptr, base8,
                                                     dinv, recs, E);
    // fused: agg layer-0 + GEMM layer-1 (block-local, no grid sync needed)
    aggemm_kernel<<<nb_ag, 512, 0, stream>>>(h, recs, row_ptr, dinv, b,
                                             wht + 16384, h2, N);
    agg_kernel<<<nb_a, 256, 0, stream>>>(h2, recs, row_ptr, dinv, b + D, out, N);
}

// Round 5
// 219.240 us; speedup vs baseline: 2.0773x; 1.0620x over previous
//
#include <hip/hip_runtime.h>
#include <hip/hip_fp16.h>

// StaticGNN: 2-layer GCN. N=50000, E=800000, D=128, fp32 in/out.
// out = relu( D^{-1/2}(A+I)D^{-1/2} (X W_l) + b_l ), x2.
// H fp16; CSR recs int2{src,coef}.
// R19 = R18 with the gather engine re-mapped for memory-level parallelism.
// R18 post-mortem: aggemm VGPR=32 (launch_bounds(512,8) strangled the batch
// pipeline) AND the edge-slot-per-quarter layout caps in-flight gathers at
// ~deg/4 ~= 4 per wave. New layout: ONE NODE PER QUARTER-WAVE, ABI=8 edges
// in flight per quarter -> 32 gathers/wave; launch_bounds relaxed to
// (512,4)/(256,4) so the batch actually lives in registers. No cross-lane
// reduction needed anymore (quarter owns the full 256B row).
// 7 dispatches: memset, count, scanA+cvtw, scanC2, gemmfill, aggemm, agg2.

#define D 128
#define WP 136   // LDS pitch (halves) for W^T tile
#define YP 136   // LDS pitch (halves) for y-tile in aggemm
#define ABI 8    // edges in flight per quarter-wave (gather pipeline depth)
#define AGT 32   // aggemm node tile (8 waves x 4 nodes)
#define NB_SCAN 196     // ceil(50000/256)

typedef _Float16 half8 __attribute__((ext_vector_type(8)));
typedef float floatx4 __attribute__((ext_vector_type(4)));

// ---------------- setup kernels ----------------

// deg8[8][n] zeroed by memset. Copy c = blockIdx&7. rank = within-copy rank.
__global__ void count_kernel(const int* __restrict__ dst, int* deg8,
                             int* __restrict__ rank, int e, int n) {
    int i = blockIdx.x * blockDim.x + threadIdx.x;
    int c = (blockIdx.x & 7) * n;
    if (i < e) rank[i] = atomicAdd(&deg8[c + dst[i]], 1);
}

// scanA: per-node total degree + per-copy exclusive bases; block sums -> partial.
// cvtw (W fp32 -> W^T fp16) fused as independent block-range tail.
__global__ __launch_bounds__(256) void scanA_cvtw_kernel(const int* __restrict__ deg8,
                                                         int* __restrict__ degT,
                                                         int* __restrict__ base8,
                                                         int* __restrict__ partial,
                                                         int n, int nbs,
                                                         const float* __restrict__ W,
                                                         __half* __restrict__ WhT) {
    __shared__ int red[4];
    int tid = threadIdx.x;
    int bid = blockIdx.x;
    if (bid < nbs) {
        int i = bid * 256 + tid;
        int tot = 0;
        if (i < n) {
            int run = 0;
#pragma unroll
            for (int c = 0; c < 8; ++c) {
                base8[c * n + i] = run;
                run += deg8[c * n + i];
            }
            degT[i] = run;
            tot = run;
        }
        for (int off = 32; off > 0; off >>= 1) tot += __shfl_down(tot, off, 64);
        if ((tid & 63) == 0) red[tid >> 6] = tot;
        __syncthreads();
        if (tid == 0) partial[bid] = red[0] + red[1] + red[2] + red[3];
    } else {
        // W[l][k][f] -> WhT[l][f][k]; 128 blocks x 256 threads = 32768 elems
        int id = (bid - nbs) * 256 + tid;
        int l = id >> 14;
        int rem = id & 16383;
        int f = rem >> 7;
        int k = rem & 127;
        WhT[id] = __float2half(W[l * 16384 + k * 128 + f]);
    }
}

// scanC2: scanB folded in -- every block locally scans the 196 partials,
// then does its in-block node scan. Writes row_ptr + dinv.
__global__ __launch_bounds__(256) void scanC2_kernel(const int* __restrict__ degT,
                                                     const int* __restrict__ partial,
                                                     int* __restrict__ row_ptr,
                                                     float* __restrict__ dinv, int n) {
    __shared__ int sc[256];
    __shared__ int scb[256];
    int tid = threadIdx.x;
    int bid = blockIdx.x;
    int p = (tid < NB_SCAN) ? partial[tid] : 0;
    scb[tid] = p;
    __syncthreads();
    for (int off = 1; off < 256; off <<= 1) {
        int v = (tid >= off) ? scb[tid - off] : 0;
        __syncthreads();
        scb[tid] += v;
        __syncthreads();
    }
    int i = bid * 256 + tid;
    int c = (i < n) ? degT[i] : 0;
    sc[tid] = c;
    __syncthreads();
    for (int off = 1; off < 256; off <<= 1) {
        int v = (tid >= off) ? sc[tid - off] : 0;
        __syncthreads();
        sc[tid] += v;
        __syncthreads();
    }
    if (i < n) {
        int base = ((bid == 0) ? 0 : scb[bid - 1]) + sc[tid] - c;
        row_ptr[i] = base;
        dinv[i] = rsqrtf((float)(c + 1));
    }
    if (bid == 0 && tid == 0) row_ptr[n] = scb[NB_SCAN - 1];
}

// ---------------- shared device bodies ----------------

__device__ inline void gemm_body(int bid, int tid,
                                 const float* __restrict__ Xf,
                                 const __half* __restrict__ WhT,
                                 __half* __restrict__ Hh, int n,
                                 _Float16* wlds) {
#pragma unroll
    for (int q = 0; q < 8; ++q) {
        int idx = tid + q * 256;        // 0..2047, each = 8 halves
        int row = idx >> 4;
        int col8 = (idx & 15) * 8;
        const uint2* gsrc = (const uint2*)(WhT + row * 128 + col8);
        uint2 a = gsrc[0];
        uint2 b = gsrc[1];
        uint2* ldst = (uint2*)(wlds + row * WP + col8);
        ldst[0] = a;
        ldst[1] = b;
    }
    __syncthreads();

    const int wave = tid >> 6;
    const int lane = tid & 63;
    const int m = lane & 15;
    const int quad = lane >> 4;

    const int node = bid * 64 + wave * 16 + m;
    const int node_ld = node < n ? node : (n - 1);

    half8 bfr[4];
#pragma unroll
    for (int k = 0; k < 4; ++k) {
        const float4* p = (const float4*)(Xf + (size_t)node_ld * 128 + k * 32 + quad * 8);
        float4 lo = p[0];
        float4 hi = p[1];
        half8 h;
        h[0] = (_Float16)lo.x; h[1] = (_Float16)lo.y;
        h[2] = (_Float16)lo.z; h[3] = (_Float16)lo.w;
        h[4] = (_Float16)hi.x; h[5] = (_Float16)hi.y;
        h[6] = (_Float16)hi.z; h[7] = (_Float16)hi.w;
        bfr[k] = h;
    }

    floatx4 acc[8];
#pragma unroll
    for (int f = 0; f < 8; ++f) acc[f] = (floatx4){0.f, 0.f, 0.f, 0.f};

#pragma unroll
    for (int f = 0; f < 8; ++f) {
#pragma unroll
        for (int k = 0; k < 4; ++k) {
            half8 a = *(const half8*)(wlds + (f * 16 + m) * WP + k * 32 + quad * 8);
            acc[f] = __builtin_amdgcn_mfma_f32_16x16x32_f16(a, bfr[k], acc[f], 0, 0, 0);
        }
    }

    if (node < n) {
#pragma unroll
        for (int f = 0; f < 8; ++f) {
            __half2 p0 = __floats2half2_rn(acc[f][0], acc[f][1]);
            __half2 p1 = __floats2half2_rn(acc[f][2], acc[f][3]);
            uint2 pk;
            pk.x = *(unsigned int*)&p0;
            pk.y = *(unsigned int*)&p1;
            *(uint2*)(Hh + (size_t)node * 128 + f * 16 + quad * 4) = pk;
        }
    }
}

__device__ inline void fill_body(int i,
                                 const int* __restrict__ src,
                                 const int* __restrict__ dst,
                                 const int* __restrict__ rank,
                                 const int* __restrict__ row_ptr,
                                 const int* __restrict__ base8,
                                 const float* __restrict__ dinv,
                                 int2* __restrict__ recs, int e, int n) {
    if (i < e) {
        int d = dst[i];
        int s = src[i];
        int c = (i >> 8) & 7;   // copy used by count (blockIdx&7, blockDim=256)
        int pos = row_ptr[d] + base8[c * n + d] + rank[i];
        int2 rec;
        rec.x = s;
        rec.y = __float_as_int(dinv[s] * dinv[d]);
        recs[pos] = rec;
    }
}

// ---------------- fused layer-0 GEMM + CSR fill (measured win: overlap) ----------------

__global__ __launch_bounds__(256) void gemmfill_kernel(const float* __restrict__ Xf,
                                                       const __half* __restrict__ WhT,
                                                       __half* __restrict__ Hh, int n, int nbg,
                                                       const int* __restrict__ src,
                                                       const int* __restrict__ dst,
                                                       const int* __restrict__ rank,
                                                       const int* __restrict__ row_ptr,
                                                       const int* __restrict__ base8,
                                                       const float* __restrict__ dinv,
                                                       int2* __restrict__ recs, int e) {
    __shared__ _Float16 wlds[128 * WP];
    int bid = blockIdx.x;
    int tid = threadIdx.x;
    if (bid < nbg) {
        gemm_body(bid, tid, Xf, WhT, Hh, n, wlds);
    } else {
        fill_body((bid - nbg) * 256 + tid, src, dst, rank, row_ptr, base8, dinv, recs, e, n);
    }
}

// ---------------- Aggregation core (R19: one node per quarter-wave) ----------------

__device__ inline void unpack8(uint4 u, float* f) {
    union { unsigned int x; __half2 h; } a, b, c, d;
    a.x = u.x; b.x = u.y; c.x = u.z; d.x = u.w;
    float2 f0 = __half22float2(a.h);
    float2 f1 = __half22float2(b.h);
    float2 f2 = __half22float2(c.h);
    float2 f3 = __half22float2(d.h);
    f[0] = f0.x; f[1] = f0.y; f[2] = f1.x; f[3] = f1.y;
    f[4] = f2.x; f[5] = f2.y; f[6] = f3.x; f[7] = f3.y;
}

// Quarter-wave walks node v's full edge list, ABI edges in flight.
// Lane fl holds features [fl*8, fl*8+8). acc = complete row sum (no reduce).
__device__ inline void agg_row_q(int v, int fl,
                                 const uint4* __restrict__ H16,
                                 const int2* __restrict__ recs,
                                 const int* __restrict__ row_ptr,
                                 const float* __restrict__ dinv,
                                 float* acc) {
    {
        float di = dinv[v];
        float selfc = di * di;
        uint4 hv = H16[(size_t)v * 16 + fl];
        float f[8]; unpack8(hv, f);
#pragma unroll
        for (int t = 0; t < 8; ++t) acc[t] = f[t] * selfc;
    }

    int e0 = row_ptr[v];
    int e1 = row_ptr[v + 1];
    int e = e0;
    for (; e + ABI <= e1; e += ABI) {
        int2 r[ABI]; uint4 hu[ABI];
#pragma unroll
        for (int j = 0; j < ABI; ++j) r[j] = recs[e + j];      // quarter-uniform, HW broadcast
#pragma unroll
        for (int j = 0; j < ABI; ++j) hu[j] = H16[(size_t)r[j].x * 16 + fl];
#pragma unroll
        for (int j = 0; j < ABI; ++j) {
            float c = __int_as_float(r[j].y);
            float f[8]; unpack8(hu[j], f);
#pragma unroll
            for (int t = 0; t < 8; ++t) acc[t] = fmaf(f[t], c, acc[t]);
        }
    }
    if (e < e1) {
        int2 r[ABI]; uint4 hu[ABI]; bool act[ABI];
#pragma unroll
        for (int j = 0; j < ABI; ++j) {
            act[j] = (e + j) < e1;
            if (act[j]) r[j] = recs[e + j];
        }
#pragma unroll
        for (int j = 0; j < ABI; ++j) {
            if (act[j]) hu[j] = H16[(size_t)r[j].x * 16 + fl];
        }
#pragma unroll
        for (int j = 0; j < ABI; ++j) {
            if (act[j]) {
                float c = __int_as_float(r[j].y);
                float f[8]; unpack8(hu[j], f);
#pragma unroll
                for (int t = 0; t < 8; ++t) acc[t] = fmaf(f[t], c, acc[t]);
            }
        }
    }
}

// Standalone agg (layer 1 -> fp32 out). 4 waves x 4 nodes = 16 nodes/block.
__global__ __launch_bounds__(256, 4) void agg_kernel(const __half* __restrict__ H,
                                                     const int2* __restrict__ recs,
                                                     const int* __restrict__ row_ptr,
                                                     const float* __restrict__ dinv,
                                                     const float* __restrict__ bias,
                                                     float* __restrict__ YF, int n) {
    int wave = threadIdx.x >> 6;
    int lane = threadIdx.x & 63;
    int qw = lane >> 4;
    int fl = lane & 15;
    int v = blockIdx.x * 16 + wave * 4 + qw;
    if (v >= n) return;

    const uint4* H16 = (const uint4*)H;
    float acc[8];
    agg_row_q(v, fl, H16, recs, row_ptr, dinv, acc);

    const float4* B4 = (const float4*)bias;
    float4 b0 = B4[fl * 2];
    float4 b1 = B4[fl * 2 + 1];
    float4* Y4 = (float4*)YF;
    Y4[(size_t)v * 32 + fl * 2] = make_float4(
        fmaxf(acc[0] + b0.x, 0.f), fmaxf(acc[1] + b0.y, 0.f),
        fmaxf(acc[2] + b0.z, 0.f), fmaxf(acc[3] + b0.w, 0.f));
    Y4[(size_t)v * 32 + fl * 2 + 1] = make_float4(
        fmaxf(acc[4] + b1.x, 0.f), fmaxf(acc[5] + b1.y, 0.f),
        fmaxf(acc[6] + b1.z, 0.f), fmaxf(acc[7] + b1.w, 0.f));
}

// ---------------- fused agg(layer0) + GEMM(layer1), 32-node tile ----------------
// Block g: 8 waves x 4 nodes (one per quarter-wave) -> LDS y-tile, block-local
// barrier, then 32x128 @ W2 MFMA tile. Output -> H2 (NOT H: other blocks
// still gather from H).
__global__ __launch_bounds__(512, 4) void aggemm_kernel(
    const __half* __restrict__ H,
    const int2* __restrict__ recs,
    const int* __restrict__ row_ptr,
    const float* __restrict__ dinv,
    const float* __restrict__ bias,       // layer-0 bias
    const __half* __restrict__ WhT2,      // layer-1 W^T
    __half* __restrict__ H2, int n) {
    __shared__ _Float16 yt[AGT * YP];
    const int tid = threadIdx.x;
    const int wave = tid >> 6;
    const int lane = tid & 63;
    const int qw = lane >> 4;
    const int fl = lane & 15;
    const int g = blockIdx.x;
    const uint4* H16 = (const uint4*)H;

    // ---- phase 1: one node per quarter-wave into y-tile ----
    {
        const float4* B4 = (const float4*)bias;
        float4 b0 = B4[fl * 2];
        float4 b1 = B4[fl * 2 + 1];
        int r = wave * 4 + qw;           // local row 0..31
        int v = g * AGT + r;
        if (v < n) {
            float acc[8];
            agg_row_q(v, fl, H16, recs, row_ptr, dinv, acc);
            __half2 p0 = __floats2half2_rn(fmaxf(acc[0] + b0.x, 0.f), fmaxf(acc[1] + b0.y, 0.f));
            __half2 p1 = __floats2half2_rn(fmaxf(acc[2] + b0.z, 0.f), fmaxf(acc[3] + b0.w, 0.f));
            __half2 p2 = __floats2half2_rn(fmaxf(acc[4] + b1.x, 0.f), fmaxf(acc[5] + b1.y, 0.f));
            __half2 p3 = __floats2half2_rn(fmaxf(acc[6] + b1.z, 0.f), fmaxf(acc[7] + b1.w, 0.f));
            uint4 pk;
            pk.x = *(unsigned int*)&p0;
            pk.y = *(unsigned int*)&p1;
            pk.z = *(unsigned int*)&p2;
            pk.w = *(unsigned int*)&p3;
            *(uint4*)&yt[r * YP + fl * 8] = pk;
        } else {
            uint4 z = make_uint4(0, 0, 0, 0);
            *(uint4*)&yt[r * YP + fl * 8] = z;
        }
    }
    __syncthreads();

    // ---- phase 2: GEMM 32x128 @ W2 -> H2 ----
    const int mg = wave & 1;             // node-group (16 nodes)
    const int fh = wave >> 1;            // 2 f-blocks per wave
    const int node = g * AGT + mg * 16 + fl;

    half8 bfr[4];
#pragma unroll
    for (int k = 0; k < 4; ++k)
        bfr[k] = *(const half8*)&yt[(mg * 16 + fl) * YP + k * 32 + qw * 8];

#pragma unroll
    for (int fb = 0; fb < 2; ++fb) {
        int f = fh * 2 + fb;
        floatx4 a4 = (floatx4){0.f, 0.f, 0.f, 0.f};
#pragma unroll
        for (int k = 0; k < 4; ++k) {
            half8 a = *(const half8*)(WhT2 + ((f * 16 + fl) * 128 + k * 32 + qw * 8));
            a4 = __builtin_amdgcn_mfma_f32_16x16x32_f16(a, bfr[k], a4, 0, 0, 0);
        }
        if (node < n) {
            __half2 p0 = __floats2half2_rn(a4[0], a4[1]);
            __half2 p1 = __floats2half2_rn(a4[2], a4[3]);
            uint2 pk;
            pk.x = *(unsigned int*)&p0;
            pk.y = *(unsigned int*)&p1;
            *(uint2*)(H2 + (size_t)node * 128 + f * 16 + qw * 4) = pk;
        }
    }
}

// ---------------- launch ----------------

extern "C" void kernel_launch(void* const* d_in, const int* in_sizes, int n_in,
                              void* d_out, int out_size, void* d_ws, size_t ws_size,
                              hipStream_t stream) {
    const float* x = (const float*)d_in[0];
    const int* ei = (const int*)d_in[1];
    const float* W = (const float*)d_in[2];
    const float* b = (const float*)d_in[3];
    float* out = (float*)d_out;

    const int N = in_sizes[0] / D;       // 50000
    const int E = in_sizes[1] / 2;       // 800000

    const int* src = ei;
    const int* dst = ei + E;

    int* wsi = (int*)d_ws;
    float* wsf = (float*)d_ws;
    const size_t o_deg8 = 0;                 // 8*N ints (memset 0)
    const size_t o_degT = o_deg8 + 400000;   // N ints
    const size_t o_dinv = o_degT + 50000;    // N floats
    const size_t o_rp   = o_dinv + 50000;    // N+1 ints (pad 50016)
    const size_t o_part = o_rp + 50016;      // 256
    const size_t o_boff = o_part + 256;      // 256 (unused, layout kept)
    const size_t o_b8   = o_boff + 256;      // 8*N ints
    const size_t o_rank = o_b8 + 400000;     // E ints
    const size_t o_rec  = o_rank + 800000;   // E int2 (region 16B-aligned)
    const size_t o_h    = o_rec + 1600000;   // N*128 halves = 3.2M words
    const size_t o_wht  = o_h + 3200000;     // 2*128*128 halves = 16384 words
    const size_t o_h2   = o_wht + 16384;     // N*128 halves (layer-1 GEMM out)

    int* deg8    = wsi + o_deg8;
    int* degT    = wsi + o_degT;
    float* dinv  = wsf + o_dinv;
    int* row_ptr = wsi + o_rp;
    int* partial = wsi + o_part;
    int* base8   = wsi + o_b8;
    int* rank    = wsi + o_rank;
    int2* recs   = (int2*)(wsi + o_rec);
    __half* h    = (__half*)(wsi + o_h);
    __half* wht  = (__half*)(wsi + o_wht);
    __half* h2   = (__half*)(wsi + o_h2);

    const int nb_e = (E + 255) / 256;           // 3125
    const int nb_s = (N + 255) / 256;           // 196
    const int nb_g = (N + 63) / 64;             // 782
    const int nb_ag = (N + AGT - 1) / AGT;      // 1563
    const int nb_a = (N + 15) / 16;             // 3125 (16 nodes per 256-thr block)

    hipMemsetAsync(deg8, 0, (size_t)8 * 50000 * sizeof(int), stream);
    count_kernel<<<nb_e, 256, 0, stream>>>(dst, deg8, rank, E, N);
    scanA_cvtw_kernel<<<nb_s + 128, 256, 0, stream>>>(deg8, degT, base8, partial,
                                                      N, nb_s, W, wht);
    scanC2_kernel<<<nb_s, 256, 0, stream>>>(degT, partial, row_ptr, dinv, N);
    // fused: layer-0 GEMM (blocks [0,nb_g)) + CSR fill (blocks [nb_g,...))
    gemmfill_kernel<<<nb_g + nb_e, 256, 0, stream>>>(x, wht, h, N, nb_g,
                                                     src, dst, rank, row_ptr, base8,
                                                     dinv, recs, E);
    // fused: agg layer-0 + GEMM layer-1 (block-local, no grid sync needed)
    aggemm_kernel<<<nb_ag, 512, 0, stream>>>(h, recs, row_ptr, dinv, b,
                                             wht + 16384, h2, N);
    agg_kernel<<<nb_a, 256, 0, stream>>>(h2, recs, row_ptr, dinv, b + D, out, N);
}